// Round 9
// baseline (170.625 us; speedup 1.0000x reference)
//
#include <hip/hip_runtime.h>

// CategoryDense: out[b,c,o] = sum_i x[b,c,i] * kernel[c,i,o] + bias[c,o]
// B=8192, C=64, IN=64, OUT=64, fp32 in/out. bf16 MFMA (swapped operands),
// fp32 accum.
//
// R9: composition of proven parts. Block = (category c, 256-batch tile),
// 4 waves, grid = 2048 = 8 blocks/CU x 256 CU (one full residency round).
// k[c] -> bf16 LDS (8 KB) -> A-fragments hoisted to registers. x goes
// DIRECTLY global->reg in B-fragment shape (lane reads 32B contiguous;
// R4 evidence: FETCH = 66 MB with this pattern at grid 2048). Plain f32x4
// stores (R6 evidence: WRITE = 131 MB ideal). No x-LDS, one barrier.
// VGPR ~64 + LDS 8 KB -> wave-limited 32 waves/CU.

constexpr int C_   = 64;
constexpr int IN_  = 64;
constexpr int OUT_ = 64;
constexpr int BT   = 256;

typedef __attribute__((ext_vector_type(8))) short bf16x8;
typedef __attribute__((ext_vector_type(4))) short s16x4;
typedef __attribute__((ext_vector_type(4))) float f32x4;

__device__ __forceinline__ short f2bf(float f) {
    union { float f; unsigned u; } v; v.f = f;
    unsigned r = v.u + 0x7FFF + ((v.u >> 16) & 1);   // RNE
    return (short)(r >> 16);
}

__device__ __forceinline__ bf16x8 cvt8(f32x4 lo, f32x4 hi) {
    bf16x8 r;
    #pragma unroll
    for (int e = 0; e < 4; ++e) {
        r[e]     = f2bf(lo[e]);
        r[4 + e] = f2bf(hi[e]);
    }
    return r;
}

__global__ __launch_bounds__(256, 8)
void cat_dense_mfma5(const float* __restrict__ x,
                     const float* __restrict__ k,
                     const float* __restrict__ bias,
                     float* __restrict__ out) {
    __shared__ unsigned short ksb[IN_ * OUT_];   // 8 KB bf16, linear [i][o]

    const int tid  = threadIdx.x;
    const int wv   = tid >> 6;
    const int lane = tid & 63;
    const int c    = blockIdx.x & 63;
    const long bBase = (long)(blockIdx.x >> 6) * BT;

    const int lrow = lane & 15;   // B col = batch row; A row = out channel
    const int lkg  = lane >> 4;   // K-octet select; C row-group

    // ---- stage k[c] -> bf16 LDS (linear, coalesced) ----
    #pragma unroll
    for (int it = 0; it < 4; ++it) {
        int p = tid + it * 256;
        f32x4 v = *(const f32x4*)(k + (size_t)c * (IN_ * OUT_) + (size_t)p * 4);
        s16x4 w;
        #pragma unroll
        for (int e = 0; e < 4; ++e) w[e] = f2bf(v[e]);
        *(s16x4*)(&ksb[p * 4]) = w;
    }

    // ---- xT B-fragments direct from global: lane reads 32B contiguous ----
    const long rw = bBase + wv * 64;
    bf16x8 af[2][2][2];   // [p][mt][ksi]
    #pragma unroll
    for (int p = 0; p < 2; ++p)
      #pragma unroll
      for (int mt = 0; mt < 2; ++mt)
        #pragma unroll
        for (int ksi = 0; ksi < 2; ++ksi) {
            const float* xp = x
                + (size_t)(rw + p * 32 + mt * 16 + lrow) * (C_ * IN_)
                + (size_t)c * IN_ + ksi * 32 + lkg * 8;
            f32x4 lo = *(const f32x4*)xp;
            f32x4 hi = *(const f32x4*)(xp + 4);
            af[p][mt][ksi] = cvt8(lo, hi);
        }

    // bias: lane's 4 consecutive output cols per nt
    f32x4 bv[4];
    #pragma unroll
    for (int nt = 0; nt < 4; ++nt)
        bv[nt] = *(const f32x4*)(bias + (size_t)c * OUT_ + nt * 16 + lkg * 4);

    __syncthreads();   // only barrier: k staged

    // ---- kT A-fragments hoisted to registers ----
    // A[row=o=nt*16+lrow][k=i=ksi*32+lkg*8+j]
    bf16x8 kb[4][2];
    #pragma unroll
    for (int nt = 0; nt < 4; ++nt)
      #pragma unroll
      for (int ksi = 0; ksi < 2; ++ksi) {
        union { bf16x8 v; short s[8]; } b;
        #pragma unroll
        for (int j = 0; j < 8; ++j)
            b.s[j] = (short)ksb[(ksi * 32 + lkg * 8 + j) * OUT_ + nt * 16 + lrow];
        kb[nt][ksi] = b.v;
      }

    // ---- compute + store: two M=32 passes ----
    #pragma unroll
    for (int p = 0; p < 2; ++p) {
        f32x4 acc[2][4];
        #pragma unroll
        for (int mt = 0; mt < 2; ++mt)
          #pragma unroll
          for (int nt = 0; nt < 4; ++nt)
            acc[mt][nt] = (f32x4){0.f, 0.f, 0.f, 0.f};

        #pragma unroll
        for (int ksi = 0; ksi < 2; ++ksi)
          #pragma unroll
          for (int mt = 0; mt < 2; ++mt)
            #pragma unroll
            for (int nt = 0; nt < 4; ++nt)
                acc[mt][nt] = __builtin_amdgcn_mfma_f32_16x16x32_bf16(
                                  kb[nt][ksi], af[p][mt][ksi],
                                  acc[mt][nt], 0, 0, 0);

        // D'[row=o'=lkg*4+reg][col=batch=lrow] -> f32x4 store of 4
        // consecutive output channels
        #pragma unroll
        for (int mt = 0; mt < 2; ++mt) {
            size_t rbase = (size_t)(rw + p * 32 + mt * 16 + lrow)
                               * (C_ * OUT_)
                         + (size_t)c * OUT_ + lkg * 4;
            #pragma unroll
            for (int nt = 0; nt < 4; ++nt) {
                f32x4 o = acc[mt][nt] + bv[nt];
                *(f32x4*)(out + rbase + nt * 16) = o;
            }
        }
    }
}

extern "C" void kernel_launch(void* const* d_in, const int* in_sizes, int n_in,
                              void* d_out, int out_size, void* d_ws, size_t ws_size,
                              hipStream_t stream) {
    const float* x    = (const float*)d_in[0];
    const float* k    = (const float*)d_in[1];
    const float* bias = (const float*)d_in[2];
    float* out        = (float*)d_out;

    const int B     = in_sizes[0] / (C_ * IN_);   // 8192
    const int tiles = B / BT;                     // 32
    dim3 grid(64 * tiles);                        // 2048: c = blk & 63
    cat_dense_mfma5<<<grid, 256, 0, stream>>>(x, k, bias, out);
}

// Round 10
// 70.537 us; speedup vs baseline: 2.4190x; 2.4190x over previous
//
#include <hip/hip_runtime.h>

// CategoryDense: out[b,c,o] = sum_i x[b,c,i] * kernel[c,i,o] + bias[c,o]
// B=8192, C=64, IN=64, OUT=64, fp32 in/out. bf16 MFMA (swapped operands),
// fp32 accum.
//
// R10 = R9 with launch_bounds reverted to (256,4). R9's (256,8) capped the
// allocator at 64 VGPR < ~96 live -> scratch spill (WRITE 370MB, FETCH 186MB).
// Structure: block = (category c, 256-batch tile), 4 waves, grid=2048.
// k[c] -> bf16 LDS (8KB) -> A-frags in registers. x DIRECT global->reg in
// B-fragment shape (R4 evidence: FETCH=66MB). Plain f32x4 stores
// (R6 evidence: WRITE=131MB). One barrier.

constexpr int C_   = 64;
constexpr int IN_  = 64;
constexpr int OUT_ = 64;
constexpr int BT   = 256;

typedef __attribute__((ext_vector_type(8))) short bf16x8;
typedef __attribute__((ext_vector_type(4))) short s16x4;
typedef __attribute__((ext_vector_type(4))) float f32x4;

__device__ __forceinline__ short f2bf(float f) {
    union { float f; unsigned u; } v; v.f = f;
    unsigned r = v.u + 0x7FFF + ((v.u >> 16) & 1);   // RNE
    return (short)(r >> 16);
}

__device__ __forceinline__ bf16x8 cvt8(f32x4 lo, f32x4 hi) {
    bf16x8 r;
    #pragma unroll
    for (int e = 0; e < 4; ++e) {
        r[e]     = f2bf(lo[e]);
        r[4 + e] = f2bf(hi[e]);
    }
    return r;
}

__global__ __launch_bounds__(256, 4)
void cat_dense_mfma6(const float* __restrict__ x,
                     const float* __restrict__ k,
                     const float* __restrict__ bias,
                     float* __restrict__ out) {
    __shared__ unsigned short ksb[IN_ * OUT_];   // 8 KB bf16, linear [i][o]

    const int tid  = threadIdx.x;
    const int wv   = tid >> 6;
    const int lane = tid & 63;
    const int c    = blockIdx.x & 63;
    const long bBase = (long)(blockIdx.x >> 6) * BT;

    const int lrow = lane & 15;   // B col = batch row; A row = out channel
    const int lkg  = lane >> 4;   // K-octet select; C row-group

    // ---- stage k[c] -> bf16 LDS (linear, coalesced) ----
    #pragma unroll
    for (int it = 0; it < 4; ++it) {
        int p = tid + it * 256;
        f32x4 v = *(const f32x4*)(k + (size_t)c * (IN_ * OUT_) + (size_t)p * 4);
        s16x4 w;
        #pragma unroll
        for (int e = 0; e < 4; ++e) w[e] = f2bf(v[e]);
        *(s16x4*)(&ksb[p * 4]) = w;
    }

    // ---- xT B-fragments direct from global: lane reads 32B contiguous ----
    const long rw = bBase + wv * 64;
    bf16x8 af[2][2][2];   // [p][mt][ksi]
    #pragma unroll
    for (int p = 0; p < 2; ++p)
      #pragma unroll
      for (int mt = 0; mt < 2; ++mt)
        #pragma unroll
        for (int ksi = 0; ksi < 2; ++ksi) {
            const float* xp = x
                + (size_t)(rw + p * 32 + mt * 16 + lrow) * (C_ * IN_)
                + (size_t)c * IN_ + ksi * 32 + lkg * 8;
            f32x4 lo = *(const f32x4*)xp;
            f32x4 hi = *(const f32x4*)(xp + 4);
            af[p][mt][ksi] = cvt8(lo, hi);
        }

    // bias: lane's 4 consecutive output cols per nt
    f32x4 bv[4];
    #pragma unroll
    for (int nt = 0; nt < 4; ++nt)
        bv[nt] = *(const f32x4*)(bias + (size_t)c * OUT_ + nt * 16 + lkg * 4);

    __syncthreads();   // only barrier: k staged

    // ---- kT A-fragments hoisted to registers ----
    // A[row=o=nt*16+lrow][k=i=ksi*32+lkg*8+j]
    bf16x8 kb[4][2];
    #pragma unroll
    for (int nt = 0; nt < 4; ++nt)
      #pragma unroll
      for (int ksi = 0; ksi < 2; ++ksi) {
        union { bf16x8 v; short s[8]; } b;
        #pragma unroll
        for (int j = 0; j < 8; ++j)
            b.s[j] = (short)ksb[(ksi * 32 + lkg * 8 + j) * OUT_ + nt * 16 + lrow];
        kb[nt][ksi] = b.v;
      }

    // ---- compute + store: two M=32 passes ----
    #pragma unroll
    for (int p = 0; p < 2; ++p) {
        f32x4 acc[2][4];
        #pragma unroll
        for (int mt = 0; mt < 2; ++mt)
          #pragma unroll
          for (int nt = 0; nt < 4; ++nt)
            acc[mt][nt] = (f32x4){0.f, 0.f, 0.f, 0.f};

        #pragma unroll
        for (int ksi = 0; ksi < 2; ++ksi)
          #pragma unroll
          for (int mt = 0; mt < 2; ++mt)
            #pragma unroll
            for (int nt = 0; nt < 4; ++nt)
                acc[mt][nt] = __builtin_amdgcn_mfma_f32_16x16x32_bf16(
                                  kb[nt][ksi], af[p][mt][ksi],
                                  acc[mt][nt], 0, 0, 0);

        // D'[row=o'=lkg*4+reg][col=batch=lrow] -> f32x4 store of 4
        // consecutive output channels
        #pragma unroll
        for (int mt = 0; mt < 2; ++mt) {
            size_t rbase = (size_t)(rw + p * 32 + mt * 16 + lrow)
                               * (C_ * OUT_)
                         + (size_t)c * OUT_ + lkg * 4;
            #pragma unroll
            for (int nt = 0; nt < 4; ++nt) {
                f32x4 o = acc[mt][nt] + bv[nt];
                *(f32x4*)(out + rbase + nt * 16) = o;
            }
        }
    }
}

extern "C" void kernel_launch(void* const* d_in, const int* in_sizes, int n_in,
                              void* d_out, int out_size, void* d_ws, size_t ws_size,
                              hipStream_t stream) {
    const float* x    = (const float*)d_in[0];
    const float* k    = (const float*)d_in[1];
    const float* bias = (const float*)d_in[2];
    float* out        = (float*)d_out;

    const int B     = in_sizes[0] / (C_ * IN_);   // 8192
    const int tiles = B / BT;                     // 32
    dim3 grid(64 * tiles);                        // 2048: c = blk & 63
    cat_dense_mfma6<<<grid, 256, 0, stream>>>(x, k, bias, out);
}

// Round 11
// 59.915 us; speedup vs baseline: 2.8478x; 1.1773x over previous
//
#include <hip/hip_runtime.h>

// CategoryDense: out[b,c,o] = sum_i x[b,c,i] * kernel[c,i,o] + bias[c,o]
// B=8192, C=64, IN=64, OUT=64, fp32 in/out. bf16 MFMA (swapped operands),
// fp32 accum.
//
// R11: two-kernel design.
//  K1 (transpose_k): kernel[c][i][o] fp32 -> g_kt[c][o][i] bf16 (512 KB
//     __device__ buffer), 64 blocks, one-time ~µs cost.
//  K2 (main): ZERO LDS, ZERO barriers. x B-frags direct global->reg (R4
//     pattern, FETCH-clean), kT A-frags as 8x contiguous 16B loads
//     (L2-resident, replaces per-block k-staging + barrier + 64 scalar
//     ds_reads of R6/R10). R6-proven plain f32x4 store pattern.

constexpr int C_   = 64;
constexpr int IN_  = 64;
constexpr int OUT_ = 64;
constexpr int BT   = 256;

typedef __attribute__((ext_vector_type(8))) short bf16x8;
typedef __attribute__((ext_vector_type(4))) short s16x4;
typedef __attribute__((ext_vector_type(4))) float f32x4;

__device__ unsigned short g_kt[C_ * OUT_ * IN_];   // 512 KB: kT[c][o][i] bf16

__device__ __forceinline__ short f2bf(float f) {
    union { float f; unsigned u; } v; v.f = f;
    unsigned r = v.u + 0x7FFF + ((v.u >> 16) & 1);   // RNE
    return (short)(r >> 16);
}

__device__ __forceinline__ bf16x8 cvt8(f32x4 lo, f32x4 hi) {
    bf16x8 r;
    #pragma unroll
    for (int e = 0; e < 4; ++e) {
        r[e]     = f2bf(lo[e]);
        r[4 + e] = f2bf(hi[e]);
    }
    return r;
}

__global__ __launch_bounds__(256)
void transpose_k(const float* __restrict__ k) {
    __shared__ unsigned short ks[IN_ * OUT_];   // 8 KB bf16 [i][o]
    const int tid = threadIdx.x;
    const int c   = blockIdx.x;

    #pragma unroll
    for (int it = 0; it < 4; ++it) {
        int p = tid + it * 256;
        f32x4 v = *(const f32x4*)(k + (size_t)c * (IN_ * OUT_) + (size_t)p * 4);
        s16x4 w;
        #pragma unroll
        for (int e = 0; e < 4; ++e) w[e] = f2bf(v[e]);
        *(s16x4*)(&ks[p * 4]) = w;
    }
    __syncthreads();

    // thread t writes kT[c][o][is0..is0+16), o = t>>2, is0 = (t&3)*16
    const int o   = tid >> 2;
    const int is0 = (tid & 3) * 16;
    short tmp[16];
    #pragma unroll
    for (int j = 0; j < 16; ++j)
        tmp[j] = (short)ks[(is0 + j) * OUT_ + o];
    unsigned short* dst = &g_kt[(size_t)c * (OUT_ * IN_) + o * IN_ + is0];
    *(bf16x8*)(dst)     = *(const bf16x8*)(&tmp[0]);
    *(bf16x8*)(dst + 8) = *(const bf16x8*)(&tmp[8]);
}

__global__ __launch_bounds__(256, 4)
void cat_dense_mfma7(const float* __restrict__ x,
                     const float* __restrict__ bias,
                     float* __restrict__ out) {
    const int tid  = threadIdx.x;
    const int wv   = tid >> 6;
    const int lane = tid & 63;
    const int c    = blockIdx.x & 63;
    const long bBase = (long)(blockIdx.x >> 6) * BT;

    const int lrow = lane & 15;   // B col = batch row; A row = out channel
    const int lkg  = lane >> 4;   // K-octet select; C row-group

    // ---- xT B-fragments direct from global (HBM, long latency — issue first)
    const long rw = bBase + wv * 64;
    bf16x8 af[2][2][2];   // [p][mt][ksi]
    #pragma unroll
    for (int p = 0; p < 2; ++p)
      #pragma unroll
      for (int mt = 0; mt < 2; ++mt)
        #pragma unroll
        for (int ksi = 0; ksi < 2; ++ksi) {
            const float* xp = x
                + (size_t)(rw + p * 32 + mt * 16 + lrow) * (C_ * IN_)
                + (size_t)c * IN_ + ksi * 32 + lkg * 8;
            f32x4 lo = *(const f32x4*)xp;
            f32x4 hi = *(const f32x4*)(xp + 4);
            af[p][mt][ksi] = cvt8(lo, hi);
        }

    // ---- kT A-fragments: contiguous 16B loads, L2-resident ----
    // A[row=o=nt*16+lrow][k=i=ksi*32+lkg*8+j]
    bf16x8 kb[4][2];
    #pragma unroll
    for (int nt = 0; nt < 4; ++nt)
      #pragma unroll
      for (int ksi = 0; ksi < 2; ++ksi)
        kb[nt][ksi] = *(const bf16x8*)(
            &g_kt[(size_t)c * (OUT_ * IN_) + (nt * 16 + lrow) * IN_
                  + ksi * 32 + lkg * 8]);

    // bias: lane's 4 consecutive output cols per nt
    f32x4 bv[4];
    #pragma unroll
    for (int nt = 0; nt < 4; ++nt)
        bv[nt] = *(const f32x4*)(bias + (size_t)c * OUT_ + nt * 16 + lkg * 4);

    // ---- compute + store: two M=32 passes ----
    #pragma unroll
    for (int p = 0; p < 2; ++p) {
        f32x4 acc[2][4];
        #pragma unroll
        for (int mt = 0; mt < 2; ++mt)
          #pragma unroll
          for (int nt = 0; nt < 4; ++nt)
            acc[mt][nt] = (f32x4){0.f, 0.f, 0.f, 0.f};

        #pragma unroll
        for (int ksi = 0; ksi < 2; ++ksi)
          #pragma unroll
          for (int mt = 0; mt < 2; ++mt)
            #pragma unroll
            for (int nt = 0; nt < 4; ++nt)
                acc[mt][nt] = __builtin_amdgcn_mfma_f32_16x16x32_bf16(
                                  kb[nt][ksi], af[p][mt][ksi],
                                  acc[mt][nt], 0, 0, 0);

        // D'[row=o'=lkg*4+reg][col=batch=lrow] -> f32x4 store of 4
        // consecutive output channels
        #pragma unroll
        for (int mt = 0; mt < 2; ++mt) {
            size_t rbase = (size_t)(rw + p * 32 + mt * 16 + lrow)
                               * (C_ * OUT_)
                         + (size_t)c * OUT_ + lkg * 4;
            #pragma unroll
            for (int nt = 0; nt < 4; ++nt) {
                f32x4 o = acc[mt][nt] + bv[nt];
                *(f32x4*)(out + rbase + nt * 16) = o;
            }
        }
    }
}

extern "C" void kernel_launch(void* const* d_in, const int* in_sizes, int n_in,
                              void* d_out, int out_size, void* d_ws, size_t ws_size,
                              hipStream_t stream) {
    const float* x    = (const float*)d_in[0];
    const float* k    = (const float*)d_in[1];
    const float* bias = (const float*)d_in[2];
    float* out        = (float*)d_out;

    transpose_k<<<dim3(C_), 256, 0, stream>>>(k);

    const int B     = in_sizes[0] / (C_ * IN_);   // 8192
    const int tiles = B / BT;                     // 32
    dim3 grid(64 * tiles);                        // 2048: c = blk & 63
    cat_dense_mfma7<<<grid, 256, 0, stream>>>(x, bias, out);
}

// Round 12
// 51.180 us; speedup vs baseline: 3.3339x; 1.1707x over previous
//
#include <hip/hip_runtime.h>

// CategoryDense: out[b,c,o] = sum_i x[b,c,i] * kernel[c,i,o] + bias[c,o]
// B=8192, C=64, IN=64, OUT=64, fp32 in/out. bf16 MFMA (swapped operands).
//
// R12 = R11 + L3-preserving epilogue:
//  - out is written with NONTEMPORAL stores (evict-first) so the 128MB out
//    stream stops displacing the 128MB x stream from the 256MB L3 across
//    graph replays (R11 evidence: FETCH=66MB of 128 — half of x displaced).
//  - To avoid R5's nt partial-line write amplification (+41MB), the epilogue
//    repacks acc through per-wave LDS (8KB region, no barrier) so every
//    global store instruction covers 4 batch-rows x 256B FULL lines.
//  K1 (transpose_k): kernel -> g_kt[c][o][i] bf16, unchanged from R11.

constexpr int C_   = 64;
constexpr int IN_  = 64;
constexpr int OUT_ = 64;
constexpr int BT   = 256;

typedef __attribute__((ext_vector_type(8))) short bf16x8;
typedef __attribute__((ext_vector_type(4))) short s16x4;
typedef __attribute__((ext_vector_type(4))) float f32x4;

__device__ unsigned short g_kt[C_ * OUT_ * IN_];   // 512 KB: kT[c][o][i] bf16

__device__ __forceinline__ short f2bf(float f) {
    union { float f; unsigned u; } v; v.f = f;
    unsigned r = v.u + 0x7FFF + ((v.u >> 16) & 1);   // RNE
    return (short)(r >> 16);
}

__device__ __forceinline__ bf16x8 cvt8(f32x4 lo, f32x4 hi) {
    bf16x8 r;
    #pragma unroll
    for (int e = 0; e < 4; ++e) {
        r[e]     = f2bf(lo[e]);
        r[4 + e] = f2bf(hi[e]);
    }
    return r;
}

__global__ __launch_bounds__(256)
void transpose_k(const float* __restrict__ k) {
    __shared__ unsigned short ks[IN_ * OUT_];   // 8 KB bf16 [i][o]
    const int tid = threadIdx.x;
    const int c   = blockIdx.x;

    #pragma unroll
    for (int it = 0; it < 4; ++it) {
        int p = tid + it * 256;
        f32x4 v = *(const f32x4*)(k + (size_t)c * (IN_ * OUT_) + (size_t)p * 4);
        s16x4 w;
        #pragma unroll
        for (int e = 0; e < 4; ++e) w[e] = f2bf(v[e]);
        *(s16x4*)(&ks[p * 4]) = w;
    }
    __syncthreads();

    const int o   = tid >> 2;
    const int is0 = (tid & 3) * 16;
    short tmp[16];
    #pragma unroll
    for (int j = 0; j < 16; ++j)
        tmp[j] = (short)ks[(is0 + j) * OUT_ + o];
    unsigned short* dst = &g_kt[(size_t)c * (OUT_ * IN_) + o * IN_ + is0];
    *(bf16x8*)(dst)     = *(const bf16x8*)(&tmp[0]);
    *(bf16x8*)(dst + 8) = *(const bf16x8*)(&tmp[8]);
}

__global__ __launch_bounds__(256, 4)
void cat_dense_mfma8(const float* __restrict__ x,
                     const float* __restrict__ bias,
                     float* __restrict__ out) {
    __shared__ float rp[4][32 * 64];   // 32 KB: per-wave 8 KB repack buffer

    const int tid  = threadIdx.x;
    const int wv   = tid >> 6;
    const int lane = tid & 63;
    const int c    = blockIdx.x & 63;
    const long bBase = (long)(blockIdx.x >> 6) * BT;

    const int lrow = lane & 15;   // B col = batch row; A row = out channel
    const int lkg  = lane >> 4;   // K-octet select; C row-group

    // ---- xT B-fragments direct from global (issue first, long latency) ----
    const long rw = bBase + wv * 64;
    bf16x8 af[2][2][2];   // [p][mt][ksi]
    #pragma unroll
    for (int p = 0; p < 2; ++p)
      #pragma unroll
      for (int mt = 0; mt < 2; ++mt)
        #pragma unroll
        for (int ksi = 0; ksi < 2; ++ksi) {
            const float* xp = x
                + (size_t)(rw + p * 32 + mt * 16 + lrow) * (C_ * IN_)
                + (size_t)c * IN_ + ksi * 32 + lkg * 8;
            f32x4 lo = *(const f32x4*)xp;
            f32x4 hi = *(const f32x4*)(xp + 4);
            af[p][mt][ksi] = cvt8(lo, hi);
        }

    // ---- kT A-fragments: contiguous 16B loads, L2-resident ----
    bf16x8 kb[4][2];
    #pragma unroll
    for (int nt = 0; nt < 4; ++nt)
      #pragma unroll
      for (int ksi = 0; ksi < 2; ++ksi)
        kb[nt][ksi] = *(const bf16x8*)(
            &g_kt[(size_t)c * (OUT_ * IN_) + (nt * 16 + lrow) * IN_
                  + ksi * 32 + lkg * 8]);

    // bias: lane's 4 consecutive output cols per nt (o = nt*16 + lkg*4 ..+4)
    f32x4 bv[4];
    #pragma unroll
    for (int nt = 0; nt < 4; ++nt)
        bv[nt] = *(const f32x4*)(bias + (size_t)c * OUT_ + nt * 16 + lkg * 4);

    float* rpw = &rp[wv][0];

    // ---- two M=32 passes: MFMA -> LDS repack -> full-line nt stores ----
    #pragma unroll
    for (int p = 0; p < 2; ++p) {
        f32x4 acc[2][4];
        #pragma unroll
        for (int mt = 0; mt < 2; ++mt)
          #pragma unroll
          for (int nt = 0; nt < 4; ++nt)
            acc[mt][nt] = (f32x4){0.f, 0.f, 0.f, 0.f};

        #pragma unroll
        for (int ksi = 0; ksi < 2; ++ksi)
          #pragma unroll
          for (int mt = 0; mt < 2; ++mt)
            #pragma unroll
            for (int nt = 0; nt < 4; ++nt)
                acc[mt][nt] = __builtin_amdgcn_mfma_f32_16x16x32_bf16(
                                  kb[nt][ksi], af[p][mt][ksi],
                                  acc[mt][nt], 0, 0, 0);

        // acc(+bias) -> LDS, XOR-swizzled within each 64-word row:
        // cell (bl = mt*16+lrow, o = nt*16+lkg*4+r) at word
        //   bl*64 + ((nt*16 + lkg*4) ^ (lrow<<2)) + r
        #pragma unroll
        for (int mt = 0; mt < 2; ++mt) {
            int bl = mt * 16 + lrow;
            #pragma unroll
            for (int nt = 0; nt < 4; ++nt) {
                int off = ((nt * 16 + lkg * 4) ^ (lrow << 2));
                *(f32x4*)(&rpw[bl * 64 + off]) = acc[mt][nt] + bv[nt];
            }
        }

        // read back linearly (matching unswizzle) and store full rows:
        // instr j: 4 batch-rows x 256B contiguous each -> nt store, no
        // partial 128B lines under evict-first.
        const int m = lane & 15;    // 16B chunk within row
        const int t = lane >> 4;    // row within group of 4
        #pragma unroll
        for (int j = 0; j < 8; ++j) {
            int bl   = j * 4 + t;
            int offr = (m << 2) ^ ((bl & 15) << 2);
            f32x4 v = *(const f32x4*)(&rpw[bl * 64 + offr]);
            size_t ob = (size_t)(rw + p * 32 + bl) * (C_ * OUT_)
                      + (size_t)c * OUT_ + m * 4;
            __builtin_nontemporal_store(v, (f32x4*)(out + ob));
        }
    }
}

extern "C" void kernel_launch(void* const* d_in, const int* in_sizes, int n_in,
                              void* d_out, int out_size, void* d_ws, size_t ws_size,
                              hipStream_t stream) {
    const float* x    = (const float*)d_in[0];
    const float* k    = (const float*)d_in[1];
    const float* bias = (const float*)d_in[2];
    float* out        = (float*)d_out;

    transpose_k<<<dim3(C_), 256, 0, stream>>>(k);

    const int B     = in_sizes[0] / (C_ * IN_);   // 8192
    const int tiles = B / BT;                     // 32
    dim3 grid(64 * tiles);                        // 2048: c = blk & 63
    cat_dense_mfma8<<<grid, 256, 0, stream>>>(x, bias, out);
}